// Round 4
// baseline (223.512 us; speedup 1.0000x reference)
//
#include <hip/hip_runtime.h>
#include <math.h>

#define BATCH 64
#define H 80
#define W 80
#define C 80
#define CP4 84
#define TOPK 100
#define THRESH 2.5f
#define NBINS 4096
#define COLLECT_CAP 2048
#define SPLITS 4
#define RPT (H / SPLITS)       // 20 rows per block
#define JT 16                  // j-pixels per block tile
#define JB (W / JT)            // 5 j-tiles
#define NSEG (SPLITS * JB)     // 20 candidate segments per batch
#define SEGCAP 1024
#define BLK 320                // 5 waves; lane = jl*4 + cg (cg inner => coalesced)

// float -> monotonic sortable uint (ascending key == ascending float)
__device__ __forceinline__ unsigned int f2key(float f) {
    unsigned int u = __float_as_uint(f);
    return (u & 0x80000000u) ? ~u : (u | 0x80000000u);
}
__device__ __forceinline__ float key2f(unsigned int k) {
    unsigned int u = (k & 0x80000000u) ? (k & 0x7FFFFFFFu) : ~k;
    return __uint_as_float(u);
}

union F4 { float4 v; float a[4]; };

__device__ __forceinline__ F4 f4max(F4 x, F4 y) {
    F4 r;
    r.a[0] = fmaxf(x.a[0], y.a[0]);
    r.a[1] = fmaxf(x.a[1], y.a[1]);
    r.a[2] = fmaxf(x.a[2], y.a[2]);
    r.a[3] = fmaxf(x.a[3], y.a[3]);
    return r;
}

__device__ __forceinline__ F4 f4neg() {
    F4 r;
    r.a[0] = r.a[1] = r.a[2] = r.a[3] = -INFINITY;
    return r;
}

// Raw load of one row: center float4 (all lanes, 4-lane-contiguous 64B segments)
// + predicated halo float4 (8 of 64 lanes).
__device__ __forceinline__ void load_raw(const float* __restrict__ rowbase, int j, int hj,
                                         bool has_halo, F4& cen, F4& hv) {
    cen.v = *(const float4*)(rowbase + j * CP4);
    hv = f4neg();
    if (has_halo) hv.v = *(const float4*)(rowbase + hj * CP4);
}

// Horizontal 3-max via cross-lane bpermute (neighbors are lane +/- 4).
__device__ __forceinline__ F4 hmax3(const F4& cen, const F4& hv, bool isl, bool isr,
                                    int addrL, int addrR) {
    F4 lv, rv;
    #pragma unroll
    for (int q = 0; q < 4; ++q) {
        lv.a[q] = __int_as_float(__builtin_amdgcn_ds_bpermute(addrL, __float_as_int(cen.a[q])));
        rv.a[q] = __int_as_float(__builtin_amdgcn_ds_bpermute(addrR, __float_as_int(cen.a[q])));
    }
    #pragma unroll
    for (int q = 0; q < 4; ++q) {
        lv.a[q] = isl ? hv.a[q] : lv.a[q];   // tile-left edge: halo (-inf at j==0)
        rv.a[q] = isr ? hv.a[q] : rv.a[q];   // tile-right edge: halo (-inf at j==79)
    }
    return f4max(f4max(lv, rv), cen);
}

// Rolling vertical scan, 2-deep pipelined: load row i+2 while hmax-ing row i+1
// and comparing row i. Candidates go straight to this block's private segment
// (no cross-block atomics, no pre-zeroed counters).
__global__ __launch_bounds__(BLK) void stage1_kernel(const float* __restrict__ y,
                                                     unsigned int* __restrict__ segcnt,
                                                     uint2* __restrict__ cand,
                                                     int segcap) {
    const int jb = blockIdx.x % JB;
    const int s  = (blockIdx.x / JB) % SPLITS;
    const int b  = blockIdx.x / (JB * SPLITS);
    const int t  = threadIdx.x;
    const int lane = t & 63;
    const int wv   = t >> 6;
    const int cg   = lane & 3;             // channel subgroup (inner => coalesced)
    const int jl   = (lane >> 2) & 15;     // j within tile
    const int c4   = (wv * 4 + cg) * 4;
    const int j    = jb * JT + jl;
    const int i0   = s * RPT;
    const int seg  = b * NSEG + s * JB + jb;

    const int addrL = ((lane - 4) & 63) << 2;
    const int addrR = ((lane + 4) & 63) << 2;
    const bool isl = (jl == 0);
    const bool isr = (jl == JT - 1);
    const bool has_halo = (isl && j > 0) || (isr && j < W - 1);
    const int hj = isl ? j - 1 : j + 1;

    __shared__ unsigned int scount;
    if (t == 0) scount = 0u;
    __syncthreads();

    const float* __restrict__ yb = y + (size_t)b * H * W * CP4 + c4;
    uint2* __restrict__ myseg = cand + (size_t)seg * segcap;

    F4 rm_p, rm_c, mid_c, cen_c, hv_c, cen_d, hv_d;

    // prologue: rows i0-1, i0, i0+1  (i0+1 <= 61 < H always)
    if (i0 > 0) {
        F4 ca, ha;
        load_raw(yb + (size_t)(i0 - 1) * W * CP4, j, hj, has_halo, ca, ha);
        rm_p = hmax3(ca, ha, isl, isr, addrL, addrR);
    } else {
        rm_p = f4neg();
    }
    {
        F4 cb0, hb0;
        load_raw(yb + (size_t)i0 * W * CP4, j, hj, has_halo, cb0, hb0);
        rm_c = hmax3(cb0, hb0, isl, isr, addrL, addrR);
        mid_c = cb0;
    }
    load_raw(yb + (size_t)(i0 + 1) * W * CP4, j, hj, has_halo, cen_c, hv_c);

    for (int i = i0; i < i0 + RPT; ++i) {
        // issue load for row i+2 (hidden behind this iteration's DS+VALU)
        const int inx = i + 2;
        if (inx < H) load_raw(yb + (size_t)inx * W * CP4, j, hj, has_halo, cen_d, hv_d);
        else         { cen_d = f4neg(); hv_d = f4neg(); }

        const F4 rm_n = hmax3(cen_c, hv_c, isl, isr, addrL, addrR);

        const F4 m = f4max(f4max(rm_p, rm_c), rm_n);
        #pragma unroll
        for (int q = 0; q < 4; ++q) {
            const float cv = mid_c.a[q];
            if (cv > THRESH && cv == m.a[q]) {
                const unsigned int p = atomicAdd(&scount, 1u);
                if (p < (unsigned int)segcap) {
                    const unsigned int idx = (unsigned int)((i * W + j) * C + (c4 + q));
                    myseg[p] = make_uint2(f2key(cv), idx);
                }
            }
        }
        rm_p = rm_c; rm_c = rm_n; mid_c = cen_c; cen_c = cen_d; hv_c = hv_d;
    }

    __syncthreads();
    if (t == 0) segcnt[seg] = min(scount, (unsigned int)segcap);
}

// One block per batch: radix-histogram select of top-K among candidates,
// exact stable rank of the survivors, compute final outputs.
__global__ __launch_bounds__(256) void stage2_kernel(const float* __restrict__ y,
                                                     const unsigned int* __restrict__ segcnt,
                                                     const uint2* __restrict__ cand,
                                                     int segcap,
                                                     float* __restrict__ out) {
    const int b = blockIdx.x;
    const int t = threadIdx.x;

    __shared__ unsigned int hist[NBINS];
    __shared__ uint2 coll[COLLECT_CAP];
    __shared__ unsigned int csum[256];
    __shared__ unsigned int scnt[NSEG];
    __shared__ unsigned int sT, sM;

    if (t < NSEG) scnt[t] = min(segcnt[b * NSEG + t], (unsigned int)segcap);
    for (int q = t; q < NBINS; q += 256) hist[q] = 0u;
    if (t == 0) sM = 0u;
    __syncthreads();

    for (int sg = 0; sg < NSEG; ++sg) {
        const uint2* __restrict__ cb = cand + (size_t)(b * NSEG + sg) * segcap;
        const unsigned int n = scnt[sg];
        for (unsigned int q = t; q < n; q += 256u)
            atomicAdd(&hist[cb[q].x >> 20], 1u);
    }
    __syncthreads();

    unsigned int sacc = 0;
    #pragma unroll
    for (int q = 0; q < 16; ++q) sacc += hist[t * 16 + q];
    csum[t] = sacc;
    __syncthreads();

    if (t == 0) {
        unsigned int cum = 0;
        int T = 0;
        bool found = false;
        for (int ch = 255; ch >= 0 && !found; --ch) {
            if (cum + csum[ch] >= (unsigned int)TOPK) {
                for (int bin = ch * 16 + 15; bin >= ch * 16; --bin) {
                    cum += hist[bin];
                    if (cum >= (unsigned int)TOPK) { T = bin; found = true; break; }
                }
            } else {
                cum += csum[ch];
            }
        }
        sT = found ? (unsigned int)T : 0u;
    }
    __syncthreads();

    const unsigned int T = sT;
    for (int sg = 0; sg < NSEG; ++sg) {
        const uint2* __restrict__ cb = cand + (size_t)(b * NSEG + sg) * segcap;
        const unsigned int n = scnt[sg];
        for (unsigned int q = t; q < n; q += 256u) {
            const uint2 e = cb[q];
            if ((e.x >> 20) >= T) {
                const unsigned int p = atomicAdd(&sM, 1u);
                if (p < (unsigned int)COLLECT_CAP) coll[p] = e;
            }
        }
    }
    __syncthreads();

    const unsigned int M = min(sM, (unsigned int)COLLECT_CAP);

    // exact stable rank: score desc, index asc (matches stable argsort(-score))
    for (unsigned int q = t; q < M; q += 256u) {
        const uint2 e = coll[q];
        unsigned int r = 0;
        for (unsigned int jx = 0; jx < M; ++jx) {
            const uint2 o = coll[jx];
            r += (o.x > e.x) || (o.x == e.x && o.y < e.y);
        }
        if (r < (unsigned int)TOPK) {
            const float score = key2f(e.x);
            const unsigned int idx = e.y;
            const unsigned int c  = idx % C;
            const unsigned int j2 = (idx / C) % W;
            const unsigned int i2 = idx / (C * W);
            const float* __restrict__ p = y + ((size_t)(b * H + i2) * W + j2) * CP4;
            const float w0 = expf(p[C + 0]) - 1.0f;
            const float w1 = expf(p[C + 1]) - 1.0f;
            const float b0 = p[C + 2];
            const float b1 = p[C + 3];
            const int o1 = b * TOPK + r;
            out[o1] = score;                                              // score_k
            out[BATCH * TOPK + o1] = (float)c;                            // k
            out[2 * BATCH * TOPK + 2 * o1 + 0] = 4.0f * (float)j2 + b0;   // centers x
            out[2 * BATCH * TOPK + 2 * o1 + 1] = 4.0f * (float)i2 + b1;   // centers y
            out[4 * BATCH * TOPK + 2 * o1 + 0] = 4.0f * w0;               // wh x
            out[4 * BATCH * TOPK + 2 * o1 + 1] = 4.0f * w1;               // wh y
        }
    }

    for (unsigned int q = M + t; q < (unsigned int)TOPK; q += 256u) {
        const int o1 = b * TOPK + q;
        out[o1] = 0.0f;
        out[BATCH * TOPK + o1] = 0.0f;
        out[2 * BATCH * TOPK + 2 * o1 + 0] = 0.0f;
        out[2 * BATCH * TOPK + 2 * o1 + 1] = 0.0f;
        out[4 * BATCH * TOPK + 2 * o1 + 0] = 0.0f;
        out[4 * BATCH * TOPK + 2 * o1 + 1] = 0.0f;
    }
}

extern "C" void kernel_launch(void* const* d_in, const int* in_sizes, int n_in,
                              void* d_out, int out_size, void* d_ws, size_t ws_size,
                              hipStream_t stream) {
    const float* y = (const float*)d_in[0];
    float* out = (float*)d_out;

    unsigned int* segcnt = (unsigned int*)d_ws;              // BATCH*NSEG counts
    uint2* cand = (uint2*)((char*)d_ws + 8192);

    int segcap = SEGCAP;
    const size_t avail = ws_size > 8192 ? ws_size - 8192 : 0;
    const size_t maxseg = avail / ((size_t)BATCH * NSEG * sizeof(uint2));
    if (maxseg < (size_t)segcap) segcap = (int)maxseg;

    stage1_kernel<<<BATCH * SPLITS * JB, BLK, 0, stream>>>(y, segcnt, cand, segcap);
    stage2_kernel<<<BATCH, 256, 0, stream>>>(y, segcnt, cand, segcap, out);
}